// Round 1
// baseline (21498.978 us; speedup 1.0000x reference)
//
#include <hip/hip_runtime.h>
#include <math.h>

#define KC 32
#define HD 64
#define OB 32
#define TLEN 500
#define NB 32
#define NT 256
#define LOG2PI 1.8378770664093453f

// ws float offsets (first 64 floats = barrier region, memset to 0 by host)
#define WS_LW0 64
#define WS_LW1 96
#define WS_MU0 128
#define WS_MU1 (128 + 2048)
#define WS_PP0 (128 + 4096)
#define WS_PP1 (WS_PP0 + 131072)

__device__ __forceinline__ void gridbar(unsigned* cnt, unsigned* gen) {
  __syncthreads();
  if (threadIdx.x == 0) {
    __threadfence();
    unsigned g = __hip_atomic_load(gen, __ATOMIC_RELAXED, __HIP_MEMORY_SCOPE_AGENT);
    unsigned a = __hip_atomic_fetch_add(cnt, 1u, __ATOMIC_ACQ_REL, __HIP_MEMORY_SCOPE_AGENT);
    if (a == NB - 1) {
      __hip_atomic_store(cnt, 0u, __ATOMIC_RELAXED, __HIP_MEMORY_SCOPE_AGENT);
      __hip_atomic_fetch_add(gen, 1u, __ATOMIC_RELEASE, __HIP_MEMORY_SCOPE_AGENT);
    } else {
      while (__hip_atomic_load(gen, __ATOMIC_ACQUIRE, __HIP_MEMORY_SCOPE_AGENT) == g) {
        __builtin_amdgcn_s_sleep(2);
      }
    }
    __threadfence();
  }
  __syncthreads();
}

__global__ __launch_bounds__(NT, 1) void slds_kernel(
    const float* __restrict__ gdata, const float* __restrict__ gtl,
    const float* __restrict__ gA, const float* __restrict__ gltn,
    const float* __restrict__ gC, const float* __restrict__ glon,
    float* __restrict__ gout, float* __restrict__ ws)
{
  __shared__ __align__(16) float At[4096];   // At[g*64+r] = A[r][g]
  __shared__ __align__(16) float Ct[2048];   // Ct[d*64+h] = C[h][d]
  __shared__ __align__(16) float Pm[64*68];  // stride-68 matrix buffer
  __shared__ __align__(16) float Sc[64*68];  // scratch (AP transposed)
  __shared__ __align__(16) float pcb[2][64];
  __shared__ __align__(16) float mubar[64];
  __shared__ __align__(16) float muL[64];
  __shared__ float tl[32], rw[32], qd[64], rdv[32], yv[32];
  __shared__ float redS[2][4], redV[2][4];

  const int j = blockIdx.x, tid = threadIdx.x;
  unsigned* cnt = (unsigned*)ws;
  unsigned* gen = ((unsigned*)ws) + 1;

  // ---- one-time init ----
  for (int e = tid; e < 4096; e += NT) { int r = e >> 6, g = e & 63; At[g*64 + r] = gA[j*4096 + e]; }
  for (int e = tid; e < 2048; e += NT) { int h = e >> 5, d = e & 31; Ct[d*64 + h] = gC[e]; }
  if (tid < 64) qd[tid] = expf(gltn[tid]);
  if (tid < 32) rdv[tid] = expf(glon[tid]);
  if (tid < 32) {
    float mx = -1e30f;
    for (int i = 0; i < 32; ++i) mx = fmaxf(mx, gtl[tid*32 + i]);
    float s = 0.f;
    for (int i = 0; i < 32; ++i) s += expf(gtl[tid*32 + i] - mx);
    tl[tid] = gtl[tid*32 + j] - (mx + logf(s));   // trans_log[k][j]
  }
  __syncthreads();

  const int h  = tid >> 2, gq = tid & 3;            // obs-phase map
  const int r0 = (tid >> 4) << 2, c0 = (tid & 15) << 2;  // GEMM tile map

  #pragma unroll 1
  for (int t = 0; t < TLEN; ++t) {
    float4 Preg[4];
    float mu_h = 0.f, base_lw;

    if (t == 0) {
      if (tid < 32) yv[tid] = gdata[tid];
      #pragma unroll
      for (int u = 0; u < 4; ++u) {
        int gb = gq*16 + 4*u;
        float4 vv = make_float4(0.f,0.f,0.f,0.f);
        if (h == gb  ) vv.x = 1.f;
        if (h == gb+1) vv.y = 1.f;
        if (h == gb+2) vv.z = 1.f;
        if (h == gb+3) vv.w = 1.f;
        Preg[u] = vv;                                // P = I
      }
      base_lw = tl[0];                               // trans_log[0][j]
      __syncthreads();
    } else {
      const float* lwR = (t & 1) ? (ws + WS_LW0) : (ws + WS_LW1);
      const float* muR = (t & 1) ? (ws + WS_MU0) : (ws + WS_MU1);
      const float* ppR = (t & 1) ? (ws + WS_PP0) : (ws + WS_PP1);

      // --- r weights + new_lw (redundant per thread, deterministic) ---
      float mx = -1e30f;
      for (int k = 0; k < KC; ++k) mx = fmaxf(mx, tl[k] + lwR[k]);
      float ssum = 0.f, myex = 0.f;
      for (int k = 0; k < KC; ++k) {
        float e = expf(tl[k] + lwR[k] - mx);
        ssum += e;
        if (k == tid) myex = e;
      }
      base_lw = mx + logf(ssum);
      if (tid < 32) rw[tid] = myex / ssum;
      if (tid < 32) yv[tid] = gdata[t*32 + tid];
      __syncthreads();

      // --- mubar[g] = sum_k r[k] mu[k][g] ---
      {
        float part = 0.f;
        for (int i = 0; i < 8; ++i) { int k = gq*8 + i; part += rw[k] * muR[k*64 + h]; }
        part += __shfl_xor(part, 1); part += __shfl_xor(part, 2);
        if (gq == 0) mubar[h] = part;
      }
      __syncthreads();

      // --- mix: M = sum_k r[k] (P_k + mu mu^T) - mubar mubar^T ; mu_pred ---
      {
        float4 acc[4];
        #pragma unroll
        for (int c = 0; c < 4; ++c) acc[c] = make_float4(0.f,0.f,0.f,0.f);
        for (int k = 0; k < KC; ++k) {
          float rk = rw[k];
          const float4* src = (const float4*)(ppR + k*4096);
          #pragma unroll
          for (int c = 0; c < 4; ++c) {
            float4 v = src[c*256 + tid];
            acc[c].x += rk*v.x; acc[c].y += rk*v.y; acc[c].z += rk*v.z; acc[c].w += rk*v.w;
          }
        }
        int f = (tid*4) & 63;
        float4 mf = *(const float4*)&mubar[f];
        #pragma unroll
        for (int c = 0; c < 4; ++c) {
          int g = c*16 + (tid >> 4);
          float mg = mubar[g];
          float4 o;
          o.x = acc[c].x - mg*mf.x; o.y = acc[c].y - mg*mf.y;
          o.z = acc[c].z - mg*mf.z; o.w = acc[c].w - mg*mf.w;
          *(float4*)&Pm[g*68 + f] = o;
        }
        // mu_pred[h] = sum_g A[h][g] mubar[g] = sum_g At[g*64+h] mubar[g]
        float mp = 0.f;
        for (int i = 0; i < 16; ++i) { int g = gq*16 + i; mp += At[g*64 + h] * mubar[g]; }
        mp += __shfl_xor(mp, 1); mp += __shfl_xor(mp, 2);
        mu_h = (gq == 0) ? mp : 0.f;
      }
      __syncthreads();

      // --- GEMM1: AP = A*M, stored transposed into Sc ---
      {
        float acc[4][4] = {};
        for (int g = 0; g < 64; ++g) {
          float4 a = *(const float4*)&At[g*64 + r0];
          float4 b = *(const float4*)&Pm[g*68 + c0];
          float av[4] = {a.x,a.y,a.z,a.w};
          float bv[4] = {b.x,b.y,b.z,b.w};
          #pragma unroll
          for (int ii = 0; ii < 4; ++ii)
            #pragma unroll
            for (int jj = 0; jj < 4; ++jj) acc[ii][jj] += av[ii]*bv[jj];
        }
        #pragma unroll
        for (int jj = 0; jj < 4; ++jj) {
          float4 col = make_float4(acc[0][jj], acc[1][jj], acc[2][jj], acc[3][jj]);
          *(float4*)&Sc[(c0+jj)*68 + r0] = col;
        }
      }
      __syncthreads();

      // --- GEMM2: P = A*AP^T (+ Q diag) -> Pm ---
      {
        float acc[4][4] = {};
        for (int g = 0; g < 64; ++g) {
          float4 a = *(const float4*)&At[g*64 + r0];
          float4 b = *(const float4*)&Sc[g*68 + c0];
          float av[4] = {a.x,a.y,a.z,a.w};
          float bv[4] = {b.x,b.y,b.z,b.w};
          #pragma unroll
          for (int ii = 0; ii < 4; ++ii)
            #pragma unroll
            for (int jj = 0; jj < 4; ++jj) acc[ii][jj] += av[ii]*bv[jj];
        }
        if (r0 == c0) {
          acc[0][0] += qd[r0]; acc[1][1] += qd[r0+1];
          acc[2][2] += qd[r0+2]; acc[3][3] += qd[r0+3];
        }
        #pragma unroll
        for (int ii = 0; ii < 4; ++ii)
          *(float4*)&Pm[(r0+ii)*68 + c0] = make_float4(acc[ii][0], acc[ii][1], acc[ii][2], acc[ii][3]);
      }
      __syncthreads();

      // --- load P into registers for obs phase ---
      #pragma unroll
      for (int u = 0; u < 4; ++u) Preg[u] = *(const float4*)&Pm[h*68 + gq*16 + 4*u];
    }

    // ---- observation update: 32 sequential scalar (rank-1) Kalman updates ----
    float llacc = 0.f;
    const float4* Ct4 = (const float4*)Ct;
    #pragma unroll 1
    for (int d = 0; d < OB; ++d) {
      int par = d & 1;
      float part = 0.f;
      #pragma unroll
      for (int u = 0; u < 4; ++u) {
        float4 cc = Ct4[d*16 + gq*4 + u];
        float4 p  = Preg[u];
        part += p.x*cc.x + p.y*cc.y + p.z*cc.z + p.w*cc.w;
      }
      part += __shfl_xor(part, 1); part += __shfl_xor(part, 2);   // Pc[h]
      if (gq == 0) pcb[par][h] = part;
      float ch = Ct[d*64 + h];
      float sp = (gq == 0) ? ch * part : 0.f;
      float vp = (gq == 0) ? ch * mu_h : 0.f;
      #pragma unroll
      for (int s = 4; s < 64; s <<= 1) { sp += __shfl_xor(sp, s); vp += __shfl_xor(vp, s); }
      if ((tid & 63) == 0) { int w = tid >> 6; redS[par][w] = sp; redV[par][w] = vp; }
      __syncthreads();
      float s_all = redS[par][0] + redS[par][1] + redS[par][2] + redS[par][3] + rdv[d];
      float v_all = yv[d] - (redV[par][0] + redV[par][1] + redV[par][2] + redV[par][3]);
      float inv = 1.f / s_all;
      llacc += logf(s_all) + v_all * v_all * inv;
      float phs = part * inv;
      const float4* pcb4 = (const float4*)pcb[par];
      #pragma unroll
      for (int u = 0; u < 4; ++u) {
        float4 pg = pcb4[gq*4 + u];
        Preg[u].x -= phs*pg.x; Preg[u].y -= phs*pg.y;
        Preg[u].z -= phs*pg.z; Preg[u].w -= phs*pg.w;
      }
      if (gq == 0) mu_h += part * (v_all * inv);
    }
    float lw_j = base_lw - 0.5f * (OB * LOG2PI + llacc);

    // ---- write state: Pplus = 0.5(P+P^T) + mu mu^T, mu, lw ----
    float* lwW = (t & 1) ? (ws + WS_LW1) : (ws + WS_LW0);
    float* muW = (t & 1) ? (ws + WS_MU1) : (ws + WS_MU0);
    float* ppW = (t & 1) ? (ws + WS_PP1) : (ws + WS_PP0);
    #pragma unroll
    for (int u = 0; u < 4; ++u) *(float4*)&Pm[h*68 + gq*16 + 4*u] = Preg[u];
    if (gq == 0) muL[h] = mu_h;
    __syncthreads();
    {
      float mh = muL[h];
      #pragma unroll
      for (int u = 0; u < 4; ++u) {
        int gb = gq*16 + 4*u;
        float4 pv = Preg[u];
        float4 pt = make_float4(Pm[(gb+0)*68 + h], Pm[(gb+1)*68 + h],
                                Pm[(gb+2)*68 + h], Pm[(gb+3)*68 + h]);
        float4 m4 = *(const float4*)&muL[gb];
        float4 o;
        o.x = 0.5f*(pv.x + pt.x) + mh*m4.x;
        o.y = 0.5f*(pv.y + pt.y) + mh*m4.y;
        o.z = 0.5f*(pv.z + pt.z) + mh*m4.z;
        o.w = 0.5f*(pv.w + pt.w) + mh*m4.w;
        *(float4*)&ppW[j*4096 + h*64 + gb] = o;
      }
      if (gq == 0) muW[j*64 + h] = mu_h;
      if (tid == 0) lwW[j] = lw_j;
    }
    gridbar(cnt, gen);
  }

  // ---- final logsumexp over components ----
  if (j == 0 && tid == 0) {
    const float* lw = ((TLEN - 1) & 1) ? (ws + WS_LW1) : (ws + WS_LW0);
    float mx = -1e30f;
    for (int k = 0; k < KC; ++k) mx = fmaxf(mx, lw[k]);
    float s = 0.f;
    for (int k = 0; k < KC; ++k) s += expf(lw[k] - mx);
    gout[0] = mx + logf(s);
  }
}

extern "C" void kernel_launch(void* const* d_in, const int* in_sizes, int n_in,
                              void* d_out, int out_size, void* d_ws, size_t ws_size,
                              hipStream_t stream) {
  const float* gdata = (const float*)d_in[0];
  const float* gtl   = (const float*)d_in[1];
  const float* gA    = (const float*)d_in[2];
  const float* gltn  = (const float*)d_in[3];
  const float* gC    = (const float*)d_in[4];
  const float* glon  = (const float*)d_in[5];
  float* ws = (float*)d_ws;

  // zero the grid-barrier region (d_ws is poisoned 0xAA before every launch)
  hipMemsetAsync(d_ws, 0, 256, stream);
  hipLaunchKernelGGL(slds_kernel, dim3(NB), dim3(NT), 0, stream,
                     gdata, gtl, gA, gltn, gC, glon, (float*)d_out, ws);
}

// Round 2
// 16292.862 us; speedup vs baseline: 1.3195x; 1.3195x over previous
//
#include <hip/hip_runtime.h>
#include <math.h>

#define KC 32
#define HD 64
#define OB 32
#define TLEN 500
#define NB 32
#define NT 256
#define LOG2PI 1.8378770664093453f

// ws float offsets (first 64 floats = barrier region, memset to 0 by host)
#define WS_LW0 64
#define WS_LW1 96
#define WS_MU0 128
#define WS_MU1 2176
#define WS_PPB 4224   // float offset; bf16 PP region: 2 buffers x 131072 ushorts

__device__ __forceinline__ unsigned bfp(float x){
  unsigned u = __float_as_uint(x);
  return (u + 0x7FFFu + ((u >> 16) & 1u)) >> 16;   // RNE bf16
}
__device__ __forceinline__ unsigned packbf(float a, float b){
  return bfp(a) | (bfp(b) << 16);
}
__device__ __forceinline__ float lo16(unsigned u){ return __uint_as_float(u << 16); }
__device__ __forceinline__ float hi16(unsigned u){ return __uint_as_float(u & 0xFFFF0000u); }

__device__ __forceinline__ void gridbar(unsigned* cnt, unsigned* gen) {
  __syncthreads();
  if (threadIdx.x == 0) {
    __threadfence();   // release: drain + make state writes LLC-visible
    unsigned g = __hip_atomic_load(gen, __ATOMIC_RELAXED, __HIP_MEMORY_SCOPE_AGENT);
    unsigned a = __hip_atomic_fetch_add(cnt, 1u, __ATOMIC_RELAXED, __HIP_MEMORY_SCOPE_AGENT);
    if (a == NB - 1) {
      __hip_atomic_store(cnt, 0u, __ATOMIC_RELAXED, __HIP_MEMORY_SCOPE_AGENT);
      __hip_atomic_fetch_add(gen, 1u, __ATOMIC_RELEASE, __HIP_MEMORY_SCOPE_AGENT); // release orders cnt reset before bump
    } else {
      while (__hip_atomic_load(gen, __ATOMIC_RELAXED, __HIP_MEMORY_SCOPE_AGENT) == g)
        __builtin_amdgcn_s_sleep(1);
    }
    __threadfence();   // acquire: invalidate so state reads see fresh data
  }
  __syncthreads();
}

__global__ __launch_bounds__(NT, 1) void slds_kernel(
    const float* __restrict__ gdata, const float* __restrict__ gtl,
    const float* __restrict__ gA, const float* __restrict__ gltn,
    const float* __restrict__ gC, const float* __restrict__ glon,
    float* __restrict__ gout, float* __restrict__ ws)
{
  __shared__ __align__(16) float At[4096];    // At[g*64+r] = A[r][g]
  __shared__ __align__(16) float Ct[2048];    // Ct[d*64+h] = C[h][d]
  __shared__ __align__(16) float Cn[64*33];   // Cn[h*33+d] = C[h][d] (padded)
  __shared__ __align__(16) float Pm[64*68];
  __shared__ __align__(16) float Sc[64*68];
  __shared__ __align__(16) float WL[64*5 + 4]; // W rows, stride 5
  __shared__ __align__(16) float mbp[256];     // mubar partials [wave][64]
  __shared__ __align__(16) float mubar[64];
  __shared__ __align__(16) float muL[64];
  __shared__ float tl[32], qd[64], rdv[32], yv[32];
  __shared__ float Gbuf[16], cmPb[16];

  const int j = blockIdx.x, tid = threadIdx.x;
  unsigned* cnt = (unsigned*)ws;
  unsigned* gen = ((unsigned*)ws) + 1;
  unsigned short* ppb = (unsigned short*)(ws + WS_PPB);

  // ---- one-time init ----
  for (int e = tid; e < 4096; e += NT) { int r = e >> 6, g = e & 63; At[g*64 + r] = gA[j*4096 + e]; }
  for (int e = tid; e < 2048; e += NT) { int hh = e >> 5, dd = e & 31; Ct[dd*64 + hh] = gC[e]; Cn[hh*33 + dd] = gC[e]; }
  if (tid < 64) qd[tid] = expf(gltn[tid]);
  if (tid < 32) rdv[tid] = expf(glon[tid]);
  if (tid < 32) {
    float mx = -1e30f;
    for (int i = 0; i < 32; ++i) mx = fmaxf(mx, gtl[tid*32 + i]);
    float s = 0.f;
    for (int i = 0; i < 32; ++i) s += expf(gtl[tid*32 + i] - mx);
    tl[tid] = gtl[tid*32 + j] - (mx + logf(s));   // trans_log[k][j]
  }
  __syncthreads();

  const int h  = tid >> 2, gq = tid & 3;                 // row / col-quarter map
  const int r0 = (tid >> 4) << 2, c0 = (tid & 15) << 2;  // GEMM tile map
  const int km = tid >> 3, seg = tid & 7;                // mubar load map

  #pragma unroll 1
  for (int t = 0; t < TLEN; ++t) {
    float4 Preg[4];
    float mu_h = 0.f, base_lw;
    float llacc = 0.f;

    if (t == 0) {
      if (tid < 32) yv[tid] = gdata[tid];
      if (tid < 64) muL[tid] = 0.f;
      #pragma unroll
      for (int u = 0; u < 4; ++u) {
        int gb = gq*16 + 4*u;
        float4 vv = make_float4(0.f,0.f,0.f,0.f);
        if (h == gb  ) vv.x = 1.f;
        if (h == gb+1) vv.y = 1.f;
        if (h == gb+2) vv.z = 1.f;
        if (h == gb+3) vv.w = 1.f;
        Preg[u] = vv;                                // P = I
      }
      base_lw = tl[0];
      __syncthreads();
    } else {
      const float* lwR = (t & 1) ? (ws + WS_LW0) : (ws + WS_LW1);
      const float* muR = (t & 1) ? (ws + WS_MU0) : (ws + WS_MU1);
      const uint4* pp4 = (const uint4*)(ppb + ((t & 1) ? 0u : 131072u));

      if (tid < 32) yv[tid] = gdata[t*32 + tid];

      // early mu loads (in flight during weight computation + mix)
      const float4* mup = (const float4*)(muR + km*64 + seg*8);
      float4 m0 = mup[0], m1 = mup[1];

      // --- r weights (redundant per thread; lwR loads are broadcast) ---
      float av[32];
      #pragma unroll
      for (int k = 0; k < 32; ++k) av[k] = tl[k] + lwR[k];
      float mx = av[0];
      #pragma unroll
      for (int k = 1; k < 32; ++k) mx = fmaxf(mx, av[k]);

      // --- PP prefetch (issue before exp chain so latency overlaps) ---
      const int u4i = tid*2;
      uint4 b0a[8], b1a[8];
      #pragma unroll
      for (int p = 0; p < 8; ++p) { b0a[p] = pp4[p*512 + u4i]; b1a[p] = pp4[p*512 + u4i + 1]; }

      float ssum = 0.f;
      #pragma unroll
      for (int k = 0; k < 32; ++k) { av[k] = expf(av[k] - mx); ssum += av[k]; }
      float inv = 1.f / ssum;
      base_lw = mx + logf(ssum);

      // --- mix: acc = sum_k r_k PP_k  (thread owns row h, cols gq*16..+16) ---
      float4 acc[4];
      #pragma unroll
      for (int u = 0; u < 4; ++u) acc[u] = make_float4(0.f,0.f,0.f,0.f);
      #pragma unroll
      for (int k = 0; k < 32; ++k) {
        uint4 b0 = b0a[k & 7], b1 = b1a[k & 7];
        if (k < 24) { b0a[k & 7] = pp4[(k+8)*512 + u4i]; b1a[k & 7] = pp4[(k+8)*512 + u4i + 1]; }
        float rk = av[k] * inv;
        acc[0].x += rk*lo16(b0.x); acc[0].y += rk*hi16(b0.x);
        acc[0].z += rk*lo16(b0.y); acc[0].w += rk*hi16(b0.y);
        acc[1].x += rk*lo16(b0.z); acc[1].y += rk*hi16(b0.z);
        acc[1].z += rk*lo16(b0.w); acc[1].w += rk*hi16(b0.w);
        acc[2].x += rk*lo16(b1.x); acc[2].y += rk*hi16(b1.x);
        acc[2].z += rk*lo16(b1.y); acc[2].w += rk*hi16(b1.y);
        acc[3].x += rk*lo16(b1.z); acc[3].y += rk*hi16(b1.z);
        acc[3].z += rk*lo16(b1.w); acc[3].w += rk*hi16(b1.w);
      }

      // --- mubar partials: scale early-loaded mu by r_k, reduce over k ---
      {
        float rk2 = av[km] * inv;
        m0.x *= rk2; m0.y *= rk2; m0.z *= rk2; m0.w *= rk2;
        m1.x *= rk2; m1.y *= rk2; m1.z *= rk2; m1.w *= rk2;
        #pragma unroll
        for (int mk = 8; mk < 64; mk <<= 1) {
          m0.x += __shfl_xor(m0.x, mk); m0.y += __shfl_xor(m0.y, mk);
          m0.z += __shfl_xor(m0.z, mk); m0.w += __shfl_xor(m0.w, mk);
          m1.x += __shfl_xor(m1.x, mk); m1.y += __shfl_xor(m1.y, mk);
          m1.z += __shfl_xor(m1.z, mk); m1.w += __shfl_xor(m1.w, mk);
        }
        if ((tid & 56) == 0) {
          int w = tid >> 6;
          *(float4*)&mbp[w*64 + seg*8]     = m0;
          *(float4*)&mbp[w*64 + seg*8 + 4] = m1;
        }
      }
      __syncthreads();
      if (tid < 64) mubar[tid] = mbp[tid] + mbp[64+tid] + mbp[128+tid] + mbp[192+tid];
      __syncthreads();

      // --- M = acc - mubar mubar^T -> Pm ; mu_pred = A mubar ---
      {
        float mh_ = mubar[h];
        #pragma unroll
        for (int u = 0; u < 4; ++u) {
          float4 mc = *(const float4*)&mubar[gq*16 + u*4];
          acc[u].x -= mh_*mc.x; acc[u].y -= mh_*mc.y;
          acc[u].z -= mh_*mc.z; acc[u].w -= mh_*mc.w;
          *(float4*)&Pm[h*68 + gq*16 + u*4] = acc[u];
        }
        float mp = 0.f;
        #pragma unroll
        for (int i = 0; i < 16; ++i) { int g = gq*16 + i; mp += At[g*64 + h] * mubar[g]; }
        mp += __shfl_xor(mp, 1); mp += __shfl_xor(mp, 2);
        mu_h = mp;   // valid on all lanes (xor-reduce symmetric)
      }
      __syncthreads();

      // --- GEMM1: AP = A*M, stored transposed into Sc ---
      {
        float gacc[4][4] = {};
        for (int g = 0; g < 64; ++g) {
          float4 a = *(const float4*)&At[g*64 + r0];
          float4 b = *(const float4*)&Pm[g*68 + c0];
          float avv[4] = {a.x,a.y,a.z,a.w};
          float bvv[4] = {b.x,b.y,b.z,b.w};
          #pragma unroll
          for (int ii = 0; ii < 4; ++ii)
            #pragma unroll
            for (int jj = 0; jj < 4; ++jj) gacc[ii][jj] += avv[ii]*bvv[jj];
        }
        #pragma unroll
        for (int jj = 0; jj < 4; ++jj) {
          float4 col = make_float4(gacc[0][jj], gacc[1][jj], gacc[2][jj], gacc[3][jj]);
          *(float4*)&Sc[(c0+jj)*68 + r0] = col;
        }
      }
      __syncthreads();

      // --- GEMM2: P = A*AP^T (+ Q diag) -> Pm ---
      {
        float gacc[4][4] = {};
        for (int g = 0; g < 64; ++g) {
          float4 a = *(const float4*)&At[g*64 + r0];
          float4 b = *(const float4*)&Sc[g*68 + c0];
          float avv[4] = {a.x,a.y,a.z,a.w};
          float bvv[4] = {b.x,b.y,b.z,b.w};
          #pragma unroll
          for (int ii = 0; ii < 4; ++ii)
            #pragma unroll
            for (int jj = 0; jj < 4; ++jj) gacc[ii][jj] += avv[ii]*bvv[jj];
        }
        if (r0 == c0) {
          gacc[0][0] += qd[r0]; gacc[1][1] += qd[r0+1];
          gacc[2][2] += qd[r0+2]; gacc[3][3] += qd[r0+3];
        }
        #pragma unroll
        for (int ii = 0; ii < 4; ++ii)
          *(float4*)&Pm[(r0+ii)*68 + c0] = make_float4(gacc[ii][0], gacc[ii][1], gacc[ii][2], gacc[ii][3]);
      }
      if (gq == 0) muL[h] = mu_h;
      __syncthreads();

      #pragma unroll
      for (int u = 0; u < 4; ++u) Preg[u] = *(const float4*)&Pm[h*68 + gq*16 + 4*u];
    }

    // ---- observation update: 8 rounds of exact rank-4 block Kalman ----
    #pragma unroll 1
    for (int rnd = 0; rnd < 8; ++rnd) {
      const int d0 = rnd * 4;
      // W = P C4  (thread partial over its 16 g's, reduce over gq)
      float wv[4];
      #pragma unroll
      for (int i = 0; i < 4; ++i) {
        const float4* cc = (const float4*)&Ct[(d0+i)*64 + gq*16];
        float wi = 0.f;
        #pragma unroll
        for (int u = 0; u < 4; ++u) {
          float4 c4 = cc[u]; float4 p = Preg[u];
          wi += p.x*c4.x + p.y*c4.y + p.z*c4.z + p.w*c4.w;
        }
        wv[i] = wi;
      }
      #pragma unroll
      for (int i = 0; i < 4; ++i) { wv[i] += __shfl_xor(wv[i], 1); wv[i] += __shfl_xor(wv[i], 2); }
      if (gq == 0) {
        WL[h*5+0]=wv[0]; WL[h*5+1]=wv[1]; WL[h*5+2]=wv[2]; WL[h*5+3]=wv[3];
      }
      // cm partial: C4^T mu
      {
        float cmp_ = Cn[h*33 + d0 + gq] * muL[h];
        cmp_ += __shfl_xor(cmp_, 4); cmp_ += __shfl_xor(cmp_, 8);
        cmp_ += __shfl_xor(cmp_, 16); cmp_ += __shfl_xor(cmp_, 32);
        if ((tid & 60) == 0) cmPb[(tid >> 6)*4 + gq] = cmp_;
      }
      __syncthreads();

      // Gram G = C4^T W  (wave 0 only)
      if (tid < 64) {
        int q = tid >> 4, ii = (tid >> 2) & 3, jj = tid & 3;
        float g_ = 0.f;
        #pragma unroll
        for (int hh = 0; hh < 16; ++hh) {
          int hq = q*16 + hh;
          g_ += Cn[hq*33 + d0 + ii] * WL[hq*5 + jj];
        }
        g_ += __shfl_xor(g_, 16); g_ += __shfl_xor(g_, 32);
        if (tid < 16) Gbuf[tid] = g_;
      }
      __syncthreads();

      // redundant per-thread 4x4 Cholesky + inverse, then rank-4 update
      {
        float G10=Gbuf[4],  G20=Gbuf[8],  G21=Gbuf[9];
        float G30=Gbuf[12], G31=Gbuf[13], G32=Gbuf[14];
        float s00=Gbuf[0]+rdv[d0],  s11=Gbuf[5]+rdv[d0+1];
        float s22=Gbuf[10]+rdv[d0+2], s33=Gbuf[15]+rdv[d0+3];
        float cm0=cmPb[0]+cmPb[4]+cmPb[8]+cmPb[12];
        float cm1=cmPb[1]+cmPb[5]+cmPb[9]+cmPb[13];
        float cm2=cmPb[2]+cmPb[6]+cmPb[10]+cmPb[14];
        float cm3=cmPb[3]+cmPb[7]+cmPb[11]+cmPb[15];
        float v0_=yv[d0]-cm0, v1_=yv[d0+1]-cm1, v2_=yv[d0+2]-cm2, v3_=yv[d0+3]-cm3;

        float L00=sqrtf(s00), rr0=1.f/L00;
        float L10=G10*rr0, L20=G20*rr0, L30=G30*rr0;
        float L11=sqrtf(s11-L10*L10), rr1=1.f/L11;
        float L21=(G21-L20*L10)*rr1, L31=(G31-L30*L10)*rr1;
        float L22=sqrtf(s22-L20*L20-L21*L21), rr2=1.f/L22;
        float L32=(G32-L30*L20-L31*L21)*rr2;
        float L33=sqrtf(s33-L30*L30-L31*L31-L32*L32), rr3=1.f/L33;
        llacc += 2.f*logf(L00*L11*L22*L33);

        float m00=rr0, m11=rr1, m22=rr2, m33=rr3;
        float m10=-rr1*(L10*m00);
        float m20=-rr2*(L20*m00+L21*m10);
        float m21=-rr2*(L21*m11);
        float m30=-rr3*(L30*m00+L31*m10+L32*m20);
        float m31=-rr3*(L31*m11+L32*m21);
        float m32=-rr3*(L32*m22);

        float si00=m00*m00+m10*m10+m20*m20+m30*m30;
        float si01=m10*m11+m20*m21+m30*m31;
        float si02=m20*m22+m30*m32;
        float si03=m30*m33;
        float si11=m11*m11+m21*m21+m31*m31;
        float si12=m21*m22+m31*m32;
        float si13=m31*m33;
        float si22=m22*m22+m32*m32;
        float si23=m32*m33;
        float si33=m33*m33;

        float uu0=si00*v0_+si01*v1_+si02*v2_+si03*v3_;
        float uu1=si01*v0_+si11*v1_+si12*v2_+si13*v3_;
        float uu2=si02*v0_+si12*v1_+si22*v2_+si23*v3_;
        float uu3=si03*v0_+si13*v1_+si23*v2_+si33*v3_;
        llacc += v0_*uu0 + v1_*uu1 + v2_*uu2 + v3_*uu3;

        float wr0=wv[0], wr1=wv[1], wr2=wv[2], wr3=wv[3];
        float zr0=wr0*si00+wr1*si01+wr2*si02+wr3*si03;
        float zr1=wr0*si01+wr1*si11+wr2*si12+wr3*si13;
        float zr2=wr0*si02+wr1*si12+wr2*si22+wr3*si23;
        float zr3=wr0*si03+wr1*si13+wr2*si23+wr3*si33;

        #pragma unroll
        for (int u = 0; u < 4; ++u) {
          int gb = gq*16 + u*4;
          Preg[u].x -= zr0*WL[(gb+0)*5+0]+zr1*WL[(gb+0)*5+1]+zr2*WL[(gb+0)*5+2]+zr3*WL[(gb+0)*5+3];
          Preg[u].y -= zr0*WL[(gb+1)*5+0]+zr1*WL[(gb+1)*5+1]+zr2*WL[(gb+1)*5+2]+zr3*WL[(gb+1)*5+3];
          Preg[u].z -= zr0*WL[(gb+2)*5+0]+zr1*WL[(gb+2)*5+1]+zr2*WL[(gb+2)*5+2]+zr3*WL[(gb+2)*5+3];
          Preg[u].w -= zr0*WL[(gb+3)*5+0]+zr1*WL[(gb+3)*5+1]+zr2*WL[(gb+3)*5+2]+zr3*WL[(gb+3)*5+3];
        }
        mu_h += wr0*uu0 + wr1*uu1 + wr2*uu2 + wr3*uu3;
        if (gq == 0) muL[h] = mu_h;
      }
      __syncthreads();
    }
    float lw_j = base_lw - 0.5f * (OB * LOG2PI + llacc);

    // ---- write state: PPbf16 = 0.5(P+P^T) + mu mu^T ; mu ; lw ----
    #pragma unroll
    for (int u = 0; u < 4; ++u) *(float4*)&Pm[h*68 + gq*16 + 4*u] = Preg[u];
    __syncthreads();
    {
      float* lwW = (t & 1) ? (ws + WS_LW1) : (ws + WS_LW0);
      float* muW = (t & 1) ? (ws + WS_MU1) : (ws + WS_MU0);
      uint4* ppW = (uint4*)(ppb + ((t & 1) ? 131072u : 0u)) + (size_t)j*512;
      float mh = muL[h];
      unsigned pk[8];
      #pragma unroll
      for (int u = 0; u < 4; ++u) {
        int gb = gq*16 + 4*u;
        float4 pv = Preg[u];
        float4 pt = make_float4(Pm[(gb+0)*68 + h], Pm[(gb+1)*68 + h],
                                Pm[(gb+2)*68 + h], Pm[(gb+3)*68 + h]);
        float4 m4 = *(const float4*)&muL[gb];
        float ox = 0.5f*(pv.x + pt.x) + mh*m4.x;
        float oy = 0.5f*(pv.y + pt.y) + mh*m4.y;
        float oz = 0.5f*(pv.z + pt.z) + mh*m4.z;
        float ow = 0.5f*(pv.w + pt.w) + mh*m4.w;
        pk[u*2]   = packbf(ox, oy);
        pk[u*2+1] = packbf(oz, ow);
      }
      ppW[h*8 + gq*2]     = make_uint4(pk[0], pk[1], pk[2], pk[3]);
      ppW[h*8 + gq*2 + 1] = make_uint4(pk[4], pk[5], pk[6], pk[7]);
      if (gq == 0) muW[j*64 + h] = mu_h;
      if (tid == 0) lwW[j] = lw_j;
    }
    gridbar(cnt, gen);
  }

  // ---- final logsumexp over components ----
  if (j == 0 && tid == 0) {
    const float* lw = ((TLEN - 1) & 1) ? (ws + WS_LW1) : (ws + WS_LW0);
    float mx = -1e30f;
    for (int k = 0; k < KC; ++k) mx = fmaxf(mx, lw[k]);
    float s = 0.f;
    for (int k = 0; k < KC; ++k) s += expf(lw[k] - mx);
    gout[0] = mx + logf(s);
  }
}

extern "C" void kernel_launch(void* const* d_in, const int* in_sizes, int n_in,
                              void* d_out, int out_size, void* d_ws, size_t ws_size,
                              hipStream_t stream) {
  const float* gdata = (const float*)d_in[0];
  const float* gtl   = (const float*)d_in[1];
  const float* gA    = (const float*)d_in[2];
  const float* gltn  = (const float*)d_in[3];
  const float* gC    = (const float*)d_in[4];
  const float* glon  = (const float*)d_in[5];
  float* ws = (float*)d_ws;

  hipMemsetAsync(d_ws, 0, 256, stream);
  hipLaunchKernelGGL(slds_kernel, dim3(NB), dim3(NT), 0, stream,
                     gdata, gtl, gA, gltn, gC, glon, (float*)d_out, ws);
}